// Round 1
// baseline (637.360 us; speedup 1.0000x reference)
//
#include <hip/hip_runtime.h>
#include <hip/hip_bf16.h>
#include <stdint.h>

typedef short bf16x8 __attribute__((ext_vector_type(8)));   // 8 bf16 in 4 VGPRs (guide §3)
typedef float f32x4 __attribute__((ext_vector_type(4)));
typedef unsigned short u16;
typedef u16 u16x8 __attribute__((ext_vector_type(8)));

__device__ __forceinline__ u16 f2bf(float x) {
  __hip_bfloat16 h = __float2bfloat16(x);
  return *reinterpret_cast<u16*>(&h);
}

// async global->LDS, 16B per lane. LDS dest is wave-uniform base + lane*16 (m104/m108).
__device__ __forceinline__ void gload_lds16(const void* g, const void* lds_base) {
  __builtin_amdgcn_global_load_lds(
      (const __attribute__((address_space(1))) unsigned int*)(uintptr_t)g,
      (__attribute__((address_space(3))) unsigned int*)(uintptr_t)lds_base,
      16, 0, 0);
}

// ---------------- LayerNorm + cast to bf16 (rows of q,k,v) ----------------
__global__ __launch_bounds__(256) void ln_cast_kernel(
    const float* __restrict__ q, const float* __restrict__ k, const float* __restrict__ v,
    const float* __restrict__ lw, const float* __restrict__ lb, u16* __restrict__ out) {
  int row = blockIdx.x;  // 0..24575 (q rows, then k rows, then v rows)
  const float* x;
  if (row < 8192) x = q + (size_t)row * 768;
  else if (row < 16384) x = k + (size_t)(row - 8192) * 768;
  else x = v + (size_t)(row - 16384) * 768;
  int t = threadIdx.x;
  float a0 = x[t], a1 = x[t + 256], a2 = x[t + 512];
  __shared__ float red[4];
  __shared__ float red2[4];
  float s = a0 + a1 + a2;
  for (int o = 32; o; o >>= 1) s += __shfl_down(s, o, 64);
  if ((t & 63) == 0) red[t >> 6] = s;
  __syncthreads();
  float mean = (red[0] + red[1] + red[2] + red[3]) * (1.0f / 768.0f);
  float d0 = a0 - mean, d1 = a1 - mean, d2 = a2 - mean;
  float vs = d0 * d0 + d1 * d1 + d2 * d2;
  for (int o = 32; o; o >>= 1) vs += __shfl_down(vs, o, 64);
  if ((t & 63) == 0) red2[t >> 6] = vs;
  __syncthreads();
  float var = (red2[0] + red2[1] + red2[2] + red2[3]) * (1.0f / 768.0f);
  float rstd = rsqrtf(var + 1e-5f);
  u16* o_ = out + (size_t)row * 768;
  o_[t]       = f2bf(d0 * rstd * lw[t]       + lb[t]);
  o_[t + 256] = f2bf(d1 * rstd * lw[t + 256] + lb[t + 256]);
  o_[t + 512] = f2bf(d2 * rstd * lw[t + 512] + lb[t + 512]);
}

// ---------------- fp32 -> bf16 cast (weights) ----------------
__global__ __launch_bounds__(256) void cast_f32_bf16(const float* __restrict__ in,
                                                     u16* __restrict__ out, int n4) {
  int i = blockIdx.x * 256 + threadIdx.x;  // per float4
  if (i < n4) {
    float4 vv = ((const float4*)in)[i];
    ushort4 o;
    o.x = f2bf(vv.x); o.y = f2bf(vv.y); o.z = f2bf(vv.z); o.w = f2bf(vv.w);
    ((ushort4*)out)[i] = o;
  }
}

// ---------------- 64x64 tiled bf16 transpose: vn[8192][768] -> vnT[768][8192] ----------------
__global__ __launch_bounds__(256) void transpose64(const u16* __restrict__ in, u16* __restrict__ out) {
  __shared__ __align__(16) u16 tile[64][72];  // 144B row stride, 16B-aligned
  int b = blockIdx.x;            // 128 * 12 tiles
  int tr = b / 12, tc = b % 12;  // tr: 64-row block, tc: 64-col block
  int t = threadIdx.x;
  int r = t >> 3;                // 0..31
  int cb = (t & 7) << 3;         // 0..56
#pragma unroll
  for (int i = 0; i < 2; i++) {
    int row = r + i * 32;
    const u16* src = in + (size_t)(tr * 64 + row) * 768 + tc * 64 + cb;
    *(uint4*)&tile[row][cb] = *(const uint4*)src;
  }
  __syncthreads();
#pragma unroll
  for (int i = 0; i < 2; i++) {
    int oc = r + i * 32;  // column within tile == row of output
    u16x8 tmp;
#pragma unroll
    for (int j = 0; j < 8; j++) tmp[j] = tile[cb + j][oc];
    u16* dst = out + (size_t)(tc * 64 + oc) * 8192 + tr * 64 + cb;
    *(u16x8*)dst = tmp;
  }
}

// ---------------- row softmax: S fp32 [8192] -> P bf16 in-place (first half of row) ----------------
__global__ __launch_bounds__(256) void softmax_kernel(const float* __restrict__ S, u16* __restrict__ P) {
  __shared__ __align__(16) float row[8192];
  __shared__ float red[4];
  __shared__ float red2[4];
  int r = blockIdx.x;
  const float* src = S + (size_t)r * 8192;
  int t = threadIdx.x;
  float mx = -1e30f;
#pragma unroll
  for (int i = 0; i < 8; i++) {
    float4 v4 = ((const float4*)src)[t + i * 256];
    ((float4*)row)[t + i * 256] = v4;
    mx = fmaxf(mx, fmaxf(fmaxf(v4.x, v4.y), fmaxf(v4.z, v4.w)));
  }
  for (int o = 32; o; o >>= 1) mx = fmaxf(mx, __shfl_down(mx, o, 64));
  if ((t & 63) == 0) red[t >> 6] = mx;
  __syncthreads();
  mx = fmaxf(fmaxf(red[0], red[1]), fmaxf(red[2], red[3]));
  float sum = 0.0f;
#pragma unroll
  for (int i = 0; i < 8; i++) {
    float4 v4 = ((float4*)row)[t + i * 256];
    v4.x = expf(v4.x - mx); v4.y = expf(v4.y - mx);
    v4.z = expf(v4.z - mx); v4.w = expf(v4.w - mx);
    sum += v4.x + v4.y + v4.z + v4.w;
    ((float4*)row)[t + i * 256] = v4;
  }
  for (int o = 32; o; o >>= 1) sum += __shfl_down(sum, o, 64);
  if ((t & 63) == 0) red2[t >> 6] = sum;
  __syncthreads();
  float inv = 1.0f / (red2[0] + red2[1] + red2[2] + red2[3]);
  u16* prow = P + (size_t)r * 16384;  // bf16 row packed into first half of this row's fp32 storage
#pragma unroll
  for (int i = 0; i < 8; i++) {
    float4 v4 = ((float4*)row)[t + i * 256];
    ushort4 o;
    o.x = f2bf(v4.x * inv); o.y = f2bf(v4.y * inv);
    o.z = f2bf(v4.z * inv); o.w = f2bf(v4.w * inv);
    ((ushort4*)prow)[t + i * 256] = o;
  }
}

// ---------------- bt-GEMM: C[M][N] = A[M][K] @ B[N][K]^T ----------------
// m97 structure: 128x128 tile, BK=64, 4 waves (2x2 of 64x64), 16x16x32 bf16 MFMA,
// global_load_lds width 16, single LDS buffer, 2 barriers per K-step.
// MODE 0: bf16 out; MODE 1: f32 out * scale; MODE 2: f32 out + bias[col]
template <int MODE>
__global__ __launch_bounds__(256, 2) void gemm_bt(
    const u16* __restrict__ A, const u16* __restrict__ B, void* __restrict__ Cv,
    int M, int N, int K, int lda, int ldb, int ldc,
    float scale, const float* __restrict__ bias) {
  __shared__ __align__(16) u16 sA[128 * 64];
  __shared__ __align__(16) u16 sB[128 * 64];
  const int nTn = N >> 7;
  // bijective XCD swizzle (m204)
  int nwg = gridDim.x, orig = blockIdx.x;
  int qq = nwg >> 3, rr = nwg & 7;
  int xcd = orig & 7, loc = orig >> 3;
  int wg = (xcd < rr ? xcd * (qq + 1) : rr * (qq + 1) + (xcd - rr) * qq) + loc;
  int tm = wg / nTn, tn = wg % nTn;

  const int t = threadIdx.x, l = t & 63, w = t >> 6;
  const int wr = w >> 1, wc = w & 1;
  const int lr = l & 15, kg = (l >> 4) << 3;

  f32x4 acc[4][4];
#pragma unroll
  for (int m = 0; m < 4; m++)
#pragma unroll
    for (int n = 0; n < 4; n++) acc[m][n] = (f32x4){0.f, 0.f, 0.f, 0.f};

  const size_t rowA0 = (size_t)tm * 128;
  const size_t rowB0 = (size_t)tn * 128;
  const int nk = K >> 6;
  for (int kt = 0; kt < nk; kt++) {
    const int k0 = kt << 6;
#pragma unroll
    for (int i = 0; i < 4; i++) {
      int chunk = i * 256 + t;          // 1024 x 16B chunks per 128x64 tile
      int row = chunk >> 3;
      int col = (chunk & 7) << 3;
      gload_lds16(A + (rowA0 + row) * lda + k0 + col, (const char*)sA + (i * 256 + w * 64) * 16);
      gload_lds16(B + (rowB0 + row) * ldb + k0 + col, (const char*)sB + (i * 256 + w * 64) * 16);
    }
    __syncthreads();  // drains vmcnt -> LDS tiles ready
#pragma unroll
    for (int kk = 0; kk < 2; kk++) {
      bf16x8 af[4], bfv[4];
#pragma unroll
      for (int m = 0; m < 4; m++)
        af[m] = *(const bf16x8*)&sA[(wr * 64 + m * 16 + lr) * 64 + kk * 32 + kg];
#pragma unroll
      for (int n = 0; n < 4; n++)
        bfv[n] = *(const bf16x8*)&sB[(wc * 64 + n * 16 + lr) * 64 + kk * 32 + kg];
#pragma unroll
      for (int m = 0; m < 4; m++)
#pragma unroll
        for (int n = 0; n < 4; n++)
          acc[m][n] = __builtin_amdgcn_mfma_f32_16x16x32_bf16(af[m], bfv[n], acc[m][n], 0, 0, 0);
    }
    __syncthreads();  // all reads done before next stage overwrites LDS
  }
  // epilogue: C/D layout col=lane&15, row=(lane>>4)*4+j (m89)
#pragma unroll
  for (int m = 0; m < 4; m++) {
    int row = tm * 128 + wr * 64 + m * 16 + ((l >> 4) << 2);
#pragma unroll
    for (int n = 0; n < 4; n++) {
      int col = tn * 128 + wc * 64 + n * 16 + lr;
#pragma unroll
      for (int j = 0; j < 4; j++) {
        float vl = acc[m][n][j];
        if (MODE == 0) ((u16*)Cv)[(size_t)(row + j) * ldc + col] = f2bf(vl);
        else if (MODE == 1) ((float*)Cv)[(size_t)(row + j) * ldc + col] = vl * scale;
        else ((float*)Cv)[(size_t)(row + j) * ldc + col] = vl + bias[col];
      }
    }
  }
}

// ---------------- host ----------------
extern "C" void kernel_launch(void* const* d_in, const int* in_sizes, int n_in,
                              void* d_out, int out_size, void* d_ws, size_t ws_size,
                              hipStream_t stream) {
  const float* q  = (const float*)d_in[0];
  const float* k  = (const float*)d_in[1];
  const float* v  = (const float*)d_in[2];
  const float* lw = (const float*)d_in[3];
  const float* lb = (const float*)d_in[4];
  const float* Wq = (const float*)d_in[5];
  const float* Wp = (const float*)d_in[6];
  const float* bp = (const float*)d_in[7];

  char* ws = (char*)d_ws;
  size_t off = 0;
  auto alloc = [&](size_t b) { size_t o = off; off += (b + 255) & ~(size_t)255; return o; };
  size_t o_ln = alloc((size_t)24576 * 768 * 2);  // LN(q,k,v) bf16; later reused for vnT + attn_out
  size_t o_pj = alloc((size_t)24576 * 768 * 2);  // qn,kn,vn bf16
  size_t o_wq = alloc((size_t)768 * 768 * 2);
  size_t o_wp = alloc((size_t)768 * 768 * 2);
  u16* lnbuf = (u16*)(ws + o_ln);
  u16* pj    = (u16*)(ws + o_pj);
  u16* wqb   = (u16*)(ws + o_wq);
  u16* wpb   = (u16*)(ws + o_wp);
  u16* vnT   = lnbuf;                        // [768][8192] bf16 (lnbuf dead after qkv GEMM)
  u16* attnO = lnbuf + (size_t)8192 * 768;   // [8192][768] bf16
  size_t fixedEnd = off;

  // S stripe: R x 8192 fp32 (reused in-place as P bf16 with row stride 16384 elems)
  int R = 8192;
  while (R > 128 && fixedEnd + (size_t)R * 8192 * 4 > ws_size) R >>= 1;
  float* Sbuf = (float*)(ws + fixedEnd);

  const float scale = 0.03608439182435161f;  // 1/sqrt(768)

  ln_cast_kernel<<<dim3(24576), dim3(256), 0, stream>>>(q, k, v, lw, lb, lnbuf);
  cast_f32_bf16<<<dim3(576), dim3(256), 0, stream>>>(Wq, wqb, 147456);
  cast_f32_bf16<<<dim3(576), dim3(256), 0, stream>>>(Wp, wpb, 147456);

  // qn/kn/vn = LN(x) @ W_qkv^T : [24576,768] x [768,768]^T
  gemm_bt<0><<<dim3(1152), dim3(256), 0, stream>>>(lnbuf, wqb, (void*)pj,
      24576, 768, 768, 768, 768, 768, 1.0f, (const float*)nullptr);

  transpose64<<<dim3(1536), dim3(256), 0, stream>>>(pj + (size_t)16384 * 768, vnT);

  const int ns = 8192 / R;
  for (int s = 0; s < ns; s++) {
    // S = qn_stripe @ kn^T * scale  (fp32 out)
    gemm_bt<1><<<dim3((R / 128) * 64), dim3(256), 0, stream>>>(
        pj + (size_t)s * R * 768, pj + (size_t)8192 * 768, (void*)Sbuf,
        R, 8192, 768, 768, 768, 8192, scale, (const float*)nullptr);
    // row softmax -> P bf16 (in-place, row stride 16384 elements)
    softmax_kernel<<<dim3(R), dim3(256), 0, stream>>>(Sbuf, (u16*)Sbuf);
    // attn_out_stripe = P @ vn : A=P [R][8192] (lda 16384), B=vnT [768][8192]
    gemm_bt<0><<<dim3((R / 128) * 6), dim3(256), 0, stream>>>(
        (const u16*)Sbuf, vnT, (void*)(attnO + (size_t)s * R * 768),
        R, 768, 8192, 16384, 8192, 768, 1.0f, (const float*)nullptr);
  }

  // out = attn_out @ W_proj^T + b_proj  (fp32)
  gemm_bt<2><<<dim3(384), dim3(256), 0, stream>>>(attnO, wpb, d_out,
      8192, 768, 768, 768, 768, 768, 1.0f, bp);
}

// Round 2
// 419.021 us; speedup vs baseline: 1.5211x; 1.5211x over previous
//
#include <hip/hip_runtime.h>
#include <hip/hip_bf16.h>
#include <stdint.h>

typedef short bf16x8 __attribute__((ext_vector_type(8)));   // 8 bf16 in 4 VGPRs (guide §3)
typedef float f32x4 __attribute__((ext_vector_type(4)));
typedef unsigned short u16;
typedef u16 u16x8 __attribute__((ext_vector_type(8)));

__device__ __forceinline__ u16 f2bf(float x) {
  __hip_bfloat16 h = __float2bfloat16(x);
  return *reinterpret_cast<u16*>(&h);
}
__device__ __forceinline__ float bf2f(u16 v) {
  unsigned u = (unsigned)v << 16;
  return *reinterpret_cast<float*>(&u);
}

// async global->LDS, 16B per lane. LDS dest is wave-uniform base + lane*16 (m104/m108).
__device__ __forceinline__ void gload_lds16(const void* g, const void* lds_base) {
  __builtin_amdgcn_global_load_lds(
      (const __attribute__((address_space(1))) unsigned int*)(uintptr_t)g,
      (__attribute__((address_space(3))) unsigned int*)(uintptr_t)lds_base,
      16, 0, 0);
}

// ---------------- LayerNorm + cast to bf16 (rows of q,k,v) ----------------
__global__ __launch_bounds__(256) void ln_cast_kernel(
    const float* __restrict__ q, const float* __restrict__ k, const float* __restrict__ v,
    const float* __restrict__ lw, const float* __restrict__ lb, u16* __restrict__ out) {
  int row = blockIdx.x;  // 0..24575 (q rows, then k rows, then v rows)
  const float* x;
  if (row < 8192) x = q + (size_t)row * 768;
  else if (row < 16384) x = k + (size_t)(row - 8192) * 768;
  else x = v + (size_t)(row - 16384) * 768;
  int t = threadIdx.x;
  float a0 = x[t], a1 = x[t + 256], a2 = x[t + 512];
  __shared__ float red[4];
  __shared__ float red2[4];
  float s = a0 + a1 + a2;
  for (int o = 32; o; o >>= 1) s += __shfl_down(s, o, 64);
  if ((t & 63) == 0) red[t >> 6] = s;
  __syncthreads();
  float mean = (red[0] + red[1] + red[2] + red[3]) * (1.0f / 768.0f);
  float d0 = a0 - mean, d1 = a1 - mean, d2 = a2 - mean;
  float vs = d0 * d0 + d1 * d1 + d2 * d2;
  for (int o = 32; o; o >>= 1) vs += __shfl_down(vs, o, 64);
  if ((t & 63) == 0) red2[t >> 6] = vs;
  __syncthreads();
  float var = (red2[0] + red2[1] + red2[2] + red2[3]) * (1.0f / 768.0f);
  float rstd = rsqrtf(var + 1e-5f);
  u16* o_ = out + (size_t)row * 768;
  o_[t]       = f2bf(d0 * rstd * lw[t]       + lb[t]);
  o_[t + 256] = f2bf(d1 * rstd * lw[t + 256] + lb[t + 256]);
  o_[t + 512] = f2bf(d2 * rstd * lw[t + 512] + lb[t + 512]);
}

// ---------------- fp32 -> bf16 cast (weights) ----------------
__global__ __launch_bounds__(256) void cast_f32_bf16(const float* __restrict__ in,
                                                     u16* __restrict__ out, int n4) {
  int i = blockIdx.x * 256 + threadIdx.x;  // per float4
  if (i < n4) {
    float4 vv = ((const float4*)in)[i];
    ushort4 o;
    o.x = f2bf(vv.x); o.y = f2bf(vv.y); o.z = f2bf(vv.z); o.w = f2bf(vv.w);
    ((ushort4*)out)[i] = o;
  }
}

// ---------------- 64x64 tiled bf16 transpose: vn[8192][768] -> vnT[768][8192] ----------------
__global__ __launch_bounds__(256) void transpose64(const u16* __restrict__ in, u16* __restrict__ out) {
  __shared__ __align__(16) u16 tile[64][72];  // 144B row stride, 16B-aligned
  int b = blockIdx.x;            // 128 * 12 tiles
  int tr = b / 12, tc = b % 12;  // tr: 64-row block, tc: 64-col block
  int t = threadIdx.x;
  int r = t >> 3;                // 0..31
  int cb = (t & 7) << 3;         // 0..56
#pragma unroll
  for (int i = 0; i < 2; i++) {
    int row = r + i * 32;
    const u16* src = in + (size_t)(tr * 64 + row) * 768 + tc * 64 + cb;
    *(uint4*)&tile[row][cb] = *(const uint4*)src;
  }
  __syncthreads();
#pragma unroll
  for (int i = 0; i < 2; i++) {
    int oc = r + i * 32;  // column within tile == row of output
    u16x8 tmp;
#pragma unroll
    for (int j = 0; j < 8; j++) tmp[j] = tile[cb + j][oc];
    u16* dst = out + (size_t)(tc * 64 + oc) * 8192 + tr * 64 + cb;
    *(u16x8*)dst = tmp;
  }
}

// ---------------- row softmax on bf16 S [8192] in place, register-resident ----------------
__global__ __launch_bounds__(256) void softmax_bf16(u16* __restrict__ S) {
  __shared__ float red[4];
  __shared__ float red2[4];
  int r = blockIdx.x, t = threadIdx.x;
  u16* src = S + (size_t)r * 8192;
  float vals[32];
  float mx = -1e30f;
#pragma unroll
  for (int i = 0; i < 4; i++) {
    u16x8 v8 = *(const u16x8*)(src + ((size_t)(t + i * 256)) * 8);
#pragma unroll
    for (int j = 0; j < 8; j++) {
      float f = bf2f(v8[j]);
      vals[i * 8 + j] = f;
      mx = fmaxf(mx, f);
    }
  }
  for (int o = 32; o; o >>= 1) mx = fmaxf(mx, __shfl_down(mx, o, 64));
  if ((t & 63) == 0) red[t >> 6] = mx;
  __syncthreads();
  mx = fmaxf(fmaxf(red[0], red[1]), fmaxf(red[2], red[3]));
  float sum = 0.0f;
#pragma unroll
  for (int i = 0; i < 32; i++) {
    float e = __expf(vals[i] - mx);
    vals[i] = e;
    sum += e;
  }
  for (int o = 32; o; o >>= 1) sum += __shfl_down(sum, o, 64);
  if ((t & 63) == 0) red2[t >> 6] = sum;
  __syncthreads();
  float inv = 1.0f / (red2[0] + red2[1] + red2[2] + red2[3]);
#pragma unroll
  for (int i = 0; i < 4; i++) {
    u16x8 o8;
#pragma unroll
    for (int j = 0; j < 8; j++) o8[j] = f2bf(vals[i * 8 + j] * inv);
    *(u16x8*)(src + ((size_t)(t + i * 256)) * 8) = o8;
  }
}

// ---------------- elementwise add of two bf16 partials, in place into p0 ----------------
__global__ __launch_bounds__(256) void add_bf16(u16* __restrict__ p0, const u16* __restrict__ p1, int n8) {
  int i = blockIdx.x * 256 + threadIdx.x;
  if (i < n8) {
    u16x8 a = ((const u16x8*)p0)[i];
    u16x8 b = ((const u16x8*)p1)[i];
    u16x8 o;
#pragma unroll
    for (int j = 0; j < 8; j++) o[j] = f2bf(bf2f(a[j]) + bf2f(b[j]));
    ((u16x8*)p0)[i] = o;
  }
}

// ---------------- bt-GEMM: C[M][N] = A[M][K] @ B[N][K]^T ----------------
// m97 structure: 128x128 tile, BK=64, 4 waves (2x2 of 64x64), 16x16x32 bf16 MFMA,
// global_load_lds width 16, single LDS buffer, 2 barriers per K-step.
// blockIdx.y = K-split index: A,B advance by y*K columns, C by y*cSplitStride elems.
// MODE 0: bf16 out * scale; MODE 2: f32 out + bias[col]
template <int MODE>
__global__ __launch_bounds__(256, 2) void gemm_bt(
    const u16* __restrict__ A0, const u16* __restrict__ B0, void* __restrict__ Cv,
    int M, int N, int K, int lda, int ldb, int ldc,
    float scale, const float* __restrict__ bias, size_t cSplitStride) {
  __shared__ __align__(16) u16 sA[128 * 64];
  __shared__ __align__(16) u16 sB[128 * 64];
  const u16* A = A0 + (size_t)blockIdx.y * (size_t)K;
  const u16* B = B0 + (size_t)blockIdx.y * (size_t)K;
  const size_t cOff = (size_t)blockIdx.y * cSplitStride;
  const int nTn = N >> 7;
  // bijective XCD swizzle (m204)
  int nwg = gridDim.x, orig = blockIdx.x;
  int qq = nwg >> 3, rr = nwg & 7;
  int xcd = orig & 7, loc = orig >> 3;
  int wg = (xcd < rr ? xcd * (qq + 1) : rr * (qq + 1) + (xcd - rr) * qq) + loc;
  int tm = wg / nTn, tn = wg % nTn;

  const int t = threadIdx.x, l = t & 63, w = t >> 6;
  const int wr = w >> 1, wc = w & 1;
  const int lr = l & 15, kg = (l >> 4) << 3;

  f32x4 acc[4][4];
#pragma unroll
  for (int m = 0; m < 4; m++)
#pragma unroll
    for (int n = 0; n < 4; n++) acc[m][n] = (f32x4){0.f, 0.f, 0.f, 0.f};

  const size_t rowA0 = (size_t)tm * 128;
  const size_t rowB0 = (size_t)tn * 128;
  const int nk = K >> 6;
  for (int kt = 0; kt < nk; kt++) {
    const int k0 = kt << 6;
#pragma unroll
    for (int i = 0; i < 4; i++) {
      int chunk = i * 256 + t;          // 1024 x 16B chunks per 128x64 tile
      int row = chunk >> 3;
      int col = (chunk & 7) << 3;
      gload_lds16(A + (rowA0 + row) * lda + k0 + col, (const char*)sA + (i * 256 + w * 64) * 16);
      gload_lds16(B + (rowB0 + row) * ldb + k0 + col, (const char*)sB + (i * 256 + w * 64) * 16);
    }
    __syncthreads();  // drains vmcnt -> LDS tiles ready
#pragma unroll
    for (int kk = 0; kk < 2; kk++) {
      bf16x8 af[4], bfv[4];
#pragma unroll
      for (int m = 0; m < 4; m++)
        af[m] = *(const bf16x8*)&sA[(wr * 64 + m * 16 + lr) * 64 + kk * 32 + kg];
#pragma unroll
      for (int n = 0; n < 4; n++)
        bfv[n] = *(const bf16x8*)&sB[(wc * 64 + n * 16 + lr) * 64 + kk * 32 + kg];
#pragma unroll
      for (int m = 0; m < 4; m++)
#pragma unroll
        for (int n = 0; n < 4; n++)
          acc[m][n] = __builtin_amdgcn_mfma_f32_16x16x32_bf16(af[m], bfv[n], acc[m][n], 0, 0, 0);
    }
    __syncthreads();  // all reads done before next stage overwrites LDS
  }
  // epilogue: C/D layout col=lane&15, row=(lane>>4)*4+j (m89)
#pragma unroll
  for (int m = 0; m < 4; m++) {
    int row = tm * 128 + wr * 64 + m * 16 + ((l >> 4) << 2);
#pragma unroll
    for (int n = 0; n < 4; n++) {
      int col = tn * 128 + wc * 64 + n * 16 + lr;
#pragma unroll
      for (int j = 0; j < 4; j++) {
        float vl = acc[m][n][j];
        if (MODE == 0) ((u16*)Cv)[cOff + (size_t)(row + j) * ldc + col] = f2bf(vl * scale);
        else ((float*)Cv)[(size_t)(row + j) * ldc + col] = vl + bias[col];
      }
    }
  }
}

// ---------------- host ----------------
extern "C" void kernel_launch(void* const* d_in, const int* in_sizes, int n_in,
                              void* d_out, int out_size, void* d_ws, size_t ws_size,
                              hipStream_t stream) {
  const float* q  = (const float*)d_in[0];
  const float* k  = (const float*)d_in[1];
  const float* v  = (const float*)d_in[2];
  const float* lw = (const float*)d_in[3];
  const float* lb = (const float*)d_in[4];
  const float* Wq = (const float*)d_in[5];
  const float* Wp = (const float*)d_in[6];
  const float* bp = (const float*)d_in[7];

  char* ws = (char*)d_ws;
  size_t off = 0;
  auto alloc = [&](size_t b) { size_t o = off; off += (b + 255) & ~(size_t)255; return o; };
  size_t o_ln = alloc((size_t)24576 * 768 * 2);  // LN(q,k,v) bf16; later: vnT | p0 | p1
  size_t o_pj = alloc((size_t)24576 * 768 * 2);  // qn,kn,vn bf16
  size_t o_wq = alloc((size_t)768 * 768 * 2);
  size_t o_wp = alloc((size_t)768 * 768 * 2);
  u16* lnbuf = (u16*)(ws + o_ln);
  u16* pj    = (u16*)(ws + o_pj);
  u16* wqb   = (u16*)(ws + o_wq);
  u16* wpb   = (u16*)(ws + o_wp);
  // lnbuf region (18.87M u16) is dead after the qkv GEMM; reuse as 3 x 6.29M u16:
  const size_t NS = (size_t)8192 * 768;  // 6291456
  u16* vnT = lnbuf;            // [768][8192] bf16
  u16* p0  = lnbuf + NS;       // PV partial 0, then attn_out after reduce
  u16* p1  = lnbuf + 2 * NS;   // PV partial 1
  size_t fixedEnd = off;
  // S: full 8192x8192 bf16 (134 MB) — same footprint the fp32 R=4096 stripe used before
  u16* Sbuf = (u16*)(ws + fixedEnd);

  const float scale = 0.03608439182435161f;  // 1/sqrt(768)

  ln_cast_kernel<<<dim3(24576), dim3(256), 0, stream>>>(q, k, v, lw, lb, lnbuf);
  cast_f32_bf16<<<dim3(576), dim3(256), 0, stream>>>(Wq, wqb, 147456);
  cast_f32_bf16<<<dim3(576), dim3(256), 0, stream>>>(Wp, wpb, 147456);

  // qn/kn/vn = LN(x) @ W_qkv^T : [24576,768] x [768,768]^T
  gemm_bt<0><<<dim3(1152), dim3(256), 0, stream>>>(lnbuf, wqb, (void*)pj,
      24576, 768, 768, 768, 768, 768, 1.0f, (const float*)nullptr, 0);

  transpose64<<<dim3(1536), dim3(256), 0, stream>>>(pj + (size_t)16384 * 768, vnT);

  // S = qn @ kn^T * scale  (bf16 out, full 8192x8192)
  gemm_bt<0><<<dim3(4096), dim3(256), 0, stream>>>(
      pj, pj + NS, (void*)Sbuf,
      8192, 8192, 768, 768, 768, 8192, scale, (const float*)nullptr, 0);

  // row softmax in place (bf16 -> bf16)
  softmax_bf16<<<dim3(8192), dim3(256), 0, stream>>>(Sbuf);

  // attn_out = P @ vn, 2-way split-K: partial z sums K in [z*4096,(z+1)*4096)
  gemm_bt<0><<<dim3(384, 2), dim3(256), 0, stream>>>(
      Sbuf, vnT, (void*)p0,
      8192, 768, 4096, 8192, 8192, 768, 1.0f, (const float*)nullptr, NS);

  // p0 += p1  (bf16, in place)
  add_bf16<<<dim3(3072), dim3(256), 0, stream>>>(p0, p1, (int)(NS / 8));

  // out = attn_out @ W_proj^T + b_proj  (fp32)
  gemm_bt<2><<<dim3(384), dim3(256), 0, stream>>>(p0, wpb, d_out,
      8192, 768, 768, 768, 768, 768, 1.0f, bp, 0);
}

// Round 3
// 381.365 us; speedup vs baseline: 1.6713x; 1.0987x over previous
//
#include <hip/hip_runtime.h>
#include <hip/hip_bf16.h>
#include <stdint.h>

typedef short bf16x8 __attribute__((ext_vector_type(8)));   // 8 bf16 in 4 VGPRs (guide §3)
typedef float f32x4 __attribute__((ext_vector_type(4)));
typedef unsigned short u16;
typedef u16 u16x8 __attribute__((ext_vector_type(8)));

__device__ __forceinline__ u16 f2bf(float x) {
  __hip_bfloat16 h = __float2bfloat16(x);
  return *reinterpret_cast<u16*>(&h);
}
__device__ __forceinline__ float bf2f(u16 v) {
  unsigned u = (unsigned)v << 16;
  return *reinterpret_cast<float*>(&u);
}

// async global->LDS, 16B per lane. LDS dest is wave-uniform base + lane*16 (m104/m108).
__device__ __forceinline__ void gload_lds16(const void* g, const void* lds_base) {
  __builtin_amdgcn_global_load_lds(
      (const __attribute__((address_space(1))) unsigned int*)(uintptr_t)g,
      (__attribute__((address_space(3))) unsigned int*)(uintptr_t)lds_base,
      16, 0, 0);
}

// ---------------- LayerNorm + cast to bf16 (rows of q,k,v) ----------------
__global__ __launch_bounds__(256) void ln_cast_kernel(
    const float* __restrict__ q, const float* __restrict__ k, const float* __restrict__ v,
    const float* __restrict__ lw, const float* __restrict__ lb, u16* __restrict__ out) {
  int row = blockIdx.x;  // 0..24575 (q rows, then k rows, then v rows)
  const float* x;
  if (row < 8192) x = q + (size_t)row * 768;
  else if (row < 16384) x = k + (size_t)(row - 8192) * 768;
  else x = v + (size_t)(row - 16384) * 768;
  int t = threadIdx.x;
  float a0 = x[t], a1 = x[t + 256], a2 = x[t + 512];
  __shared__ float red[4];
  __shared__ float red2[4];
  float s = a0 + a1 + a2;
  for (int o = 32; o; o >>= 1) s += __shfl_down(s, o, 64);
  if ((t & 63) == 0) red[t >> 6] = s;
  __syncthreads();
  float mean = (red[0] + red[1] + red[2] + red[3]) * (1.0f / 768.0f);
  float d0 = a0 - mean, d1 = a1 - mean, d2 = a2 - mean;
  float vs = d0 * d0 + d1 * d1 + d2 * d2;
  for (int o = 32; o; o >>= 1) vs += __shfl_down(vs, o, 64);
  if ((t & 63) == 0) red2[t >> 6] = vs;
  __syncthreads();
  float var = (red2[0] + red2[1] + red2[2] + red2[3]) * (1.0f / 768.0f);
  float rstd = rsqrtf(var + 1e-5f);
  u16* o_ = out + (size_t)row * 768;
  o_[t]       = f2bf(d0 * rstd * lw[t]       + lb[t]);
  o_[t + 256] = f2bf(d1 * rstd * lw[t + 256] + lb[t + 256]);
  o_[t + 512] = f2bf(d2 * rstd * lw[t + 512] + lb[t + 512]);
}

// ---------------- fp32 -> bf16 cast (weights) ----------------
__global__ __launch_bounds__(256) void cast_f32_bf16(const float* __restrict__ in,
                                                     u16* __restrict__ out, int n4) {
  int i = blockIdx.x * 256 + threadIdx.x;  // per float4
  if (i < n4) {
    float4 vv = ((const float4*)in)[i];
    ushort4 o;
    o.x = f2bf(vv.x); o.y = f2bf(vv.y); o.z = f2bf(vv.z); o.w = f2bf(vv.w);
    ((ushort4*)out)[i] = o;
  }
}

// ---------------- zero fp32 buffer ----------------
__global__ __launch_bounds__(256) void zero_f32(float* __restrict__ p, int n) {
  int i = blockIdx.x * 256 + threadIdx.x;
  if (i < n) p[i] = 0.0f;
}

// ---------------- 64x64 tiled bf16 transpose: vn[8192][768] -> vnT[768][8192] ----------------
__global__ __launch_bounds__(256) void transpose64(const u16* __restrict__ in, u16* __restrict__ out) {
  __shared__ __align__(16) u16 tile[64][72];  // 144B row stride, 16B-aligned
  int b = blockIdx.x;            // 128 * 12 tiles
  int tr = b / 12, tc = b % 12;  // tr: 64-row block, tc: 64-col block
  int t = threadIdx.x;
  int r = t >> 3;                // 0..31
  int cb = (t & 7) << 3;         // 0..56
#pragma unroll
  for (int i = 0; i < 2; i++) {
    int row = r + i * 32;
    const u16* src = in + (size_t)(tr * 64 + row) * 768 + tc * 64 + cb;
    *(uint4*)&tile[row][cb] = *(const uint4*)src;
  }
  __syncthreads();
#pragma unroll
  for (int i = 0; i < 2; i++) {
    int oc = r + i * 32;  // column within tile == row of output
    u16x8 tmp;
#pragma unroll
    for (int j = 0; j < 8; j++) tmp[j] = tile[cb + j][oc];
    u16* dst = out + (size_t)(tc * 64 + oc) * 8192 + tr * 64 + cb;
    *(u16x8*)dst = tmp;
  }
}

// ---------------- sum 4 bf16 partials, scale by 1/rowsum, write bf16 ----------------
__global__ __launch_bounds__(256) void reduce4_scale(
    const u16* __restrict__ p0, const u16* __restrict__ p1,
    const u16* __restrict__ p2, const u16* __restrict__ p3,
    const float* __restrict__ rowsum, u16* __restrict__ out, int n8) {
  int i = blockIdx.x * 256 + threadIdx.x;  // per u16x8; 96 per row (768/8)
  if (i < n8) {
    float inv = 1.0f / rowsum[i / 96];
    u16x8 a = ((const u16x8*)p0)[i];
    u16x8 b = ((const u16x8*)p1)[i];
    u16x8 c = ((const u16x8*)p2)[i];
    u16x8 d = ((const u16x8*)p3)[i];
    u16x8 o;
#pragma unroll
    for (int j = 0; j < 8; j++)
      o[j] = f2bf((bf2f(a[j]) + bf2f(b[j]) + bf2f(c[j]) + bf2f(d[j])) * inv);
    ((u16x8*)out)[i] = o;
  }
}

// ---------------- bt-GEMM: C[M][N] = A[M][K] @ B[N][K]^T ----------------
// m97 structure: 128x128 tile, BK=64, 4 waves (2x2 of 64x64), 16x16x32 bf16 MFMA,
// global_load_lds width 16, single LDS buffer, 2 barriers per K-step.
// blockIdx.y = K-split index z: A,B advance by z*K cols; C = (z<2 ? C0+z*str : C1+(z-2)*str).
// MODE 0: bf16 out * scale
// MODE 1: bf16 out = exp(val*scale), + per-row sum atomics into rowsum (softmax fused, no max)
// MODE 2: f32 out + bias[col]
template <int MODE>
__global__ __launch_bounds__(256, 2) void gemm_bt(
    const u16* __restrict__ A0, const u16* __restrict__ B0,
    void* __restrict__ Cv0, void* __restrict__ Cv1,
    int M, int N, int K, int lda, int ldb, int ldc,
    float scale, const float* __restrict__ bias, float* __restrict__ rowsum,
    size_t cSplitStride) {
  __shared__ __align__(16) u16 sA[128 * 64];
  __shared__ __align__(16) u16 sB[128 * 64];
  const int z = blockIdx.y;
  const u16* A = A0 + (size_t)z * (size_t)K;
  const u16* B = B0 + (size_t)z * (size_t)K;
  u16* Cb = (z < 2) ? ((u16*)Cv0 + (size_t)z * cSplitStride)
                    : ((u16*)Cv1 + (size_t)(z - 2) * cSplitStride);
  const int nTn = N >> 7;
  // bijective XCD swizzle (m204)
  int nwg = gridDim.x, orig = blockIdx.x;
  int qq = nwg >> 3, rr = nwg & 7;
  int xcd = orig & 7, loc = orig >> 3;
  int wg = (xcd < rr ? xcd * (qq + 1) : rr * (qq + 1) + (xcd - rr) * qq) + loc;
  int tm, tn;
  if (nTn == 64 && (M >> 7) == 64) {
    // 4x4 super-block ordering: 16x16 superblocks of 4x4 tiles (~1.5 MB working set -> L2)
    int sb = wg >> 4, in_ = wg & 15;
    tm = ((sb >> 4) << 2) | (in_ >> 2);
    tn = ((sb & 15) << 2) | (in_ & 3);
  } else {
    tm = wg / nTn; tn = wg % nTn;
  }

  const int t = threadIdx.x, l = t & 63, w = t >> 6;
  const int wr = w >> 1, wc = w & 1;
  const int lr = l & 15, kg = (l >> 4) << 3;

  f32x4 acc[4][4];
#pragma unroll
  for (int m = 0; m < 4; m++)
#pragma unroll
    for (int n = 0; n < 4; n++) acc[m][n] = (f32x4){0.f, 0.f, 0.f, 0.f};

  const size_t rowA0 = (size_t)tm * 128;
  const size_t rowB0 = (size_t)tn * 128;
  const int nk = K >> 6;
  for (int kt = 0; kt < nk; kt++) {
    const int k0 = kt << 6;
#pragma unroll
    for (int i = 0; i < 4; i++) {
      int chunk = i * 256 + t;          // 1024 x 16B chunks per 128x64 tile
      int row = chunk >> 3;
      int col = (chunk & 7) << 3;
      gload_lds16(A + (rowA0 + row) * lda + k0 + col, (const char*)sA + (i * 256 + w * 64) * 16);
      gload_lds16(B + (rowB0 + row) * ldb + k0 + col, (const char*)sB + (i * 256 + w * 64) * 16);
    }
    __syncthreads();  // drains vmcnt -> LDS tiles ready
#pragma unroll
    for (int kk = 0; kk < 2; kk++) {
      bf16x8 af[4], bfv[4];
#pragma unroll
      for (int m = 0; m < 4; m++)
        af[m] = *(const bf16x8*)&sA[(wr * 64 + m * 16 + lr) * 64 + kk * 32 + kg];
#pragma unroll
      for (int n = 0; n < 4; n++)
        bfv[n] = *(const bf16x8*)&sB[(wc * 64 + n * 16 + lr) * 64 + kk * 32 + kg];
#pragma unroll
      for (int m = 0; m < 4; m++)
#pragma unroll
        for (int n = 0; n < 4; n++)
          acc[m][n] = __builtin_amdgcn_mfma_f32_16x16x32_bf16(af[m], bfv[n], acc[m][n], 0, 0, 0);
    }
    __syncthreads();  // all reads done before next stage overwrites LDS
  }
  // epilogue: C/D layout col=lane&15, row=(lane>>4)*4+j (m89)
  if (MODE == 1) {
    float rs[4][4];
#pragma unroll
    for (int m = 0; m < 4; m++)
#pragma unroll
      for (int j = 0; j < 4; j++) rs[m][j] = 0.0f;
#pragma unroll
    for (int m = 0; m < 4; m++) {
      int rowb = tm * 128 + wr * 64 + m * 16 + ((l >> 4) << 2);
#pragma unroll
      for (int n = 0; n < 4; n++) {
        int col = tn * 128 + wc * 64 + n * 16 + lr;
#pragma unroll
        for (int j = 0; j < 4; j++) {
          float e = __expf(acc[m][n][j] * scale);
          Cb[(size_t)(rowb + j) * ldc + col] = f2bf(e);
          rs[m][j] += e;
        }
      }
    }
    // reduce over the 16 lr-lanes (xor 1,2,4,8 stays within the l>>4 group), one atomic per row
#pragma unroll
    for (int m = 0; m < 4; m++) {
      int rowb = tm * 128 + wr * 64 + m * 16 + ((l >> 4) << 2);
#pragma unroll
      for (int j = 0; j < 4; j++) {
        float r = rs[m][j];
        r += __shfl_xor(r, 1);
        r += __shfl_xor(r, 2);
        r += __shfl_xor(r, 4);
        r += __shfl_xor(r, 8);
        if ((l & 15) == 0) atomicAdd(&rowsum[rowb + j], r);
      }
    }
  } else {
#pragma unroll
    for (int m = 0; m < 4; m++) {
      int row = tm * 128 + wr * 64 + m * 16 + ((l >> 4) << 2);
#pragma unroll
      for (int n = 0; n < 4; n++) {
        int col = tn * 128 + wc * 64 + n * 16 + lr;
#pragma unroll
        for (int j = 0; j < 4; j++) {
          float vl = acc[m][n][j];
          if (MODE == 0) Cb[(size_t)(row + j) * ldc + col] = f2bf(vl * scale);
          else ((float*)Cv0)[(size_t)(row + j) * ldc + col] = vl + bias[col];
        }
      }
    }
  }
}

// ---------------- host ----------------
extern "C" void kernel_launch(void* const* d_in, const int* in_sizes, int n_in,
                              void* d_out, int out_size, void* d_ws, size_t ws_size,
                              hipStream_t stream) {
  const float* q  = (const float*)d_in[0];
  const float* k  = (const float*)d_in[1];
  const float* v  = (const float*)d_in[2];
  const float* lw = (const float*)d_in[3];
  const float* lb = (const float*)d_in[4];
  const float* Wq = (const float*)d_in[5];
  const float* Wp = (const float*)d_in[6];
  const float* bp = (const float*)d_in[7];

  char* ws = (char*)d_ws;
  size_t off = 0;
  auto alloc = [&](size_t b) { size_t o = off; off += (b + 255) & ~(size_t)255; return o; };
  size_t o_ln = alloc((size_t)24576 * 768 * 2);  // LN(q,k,v) bf16; later: vnT | p0 | p1
  size_t o_pj = alloc((size_t)24576 * 768 * 2);  // qn,kn,vn bf16; vn region later: rowsum
  size_t o_wq = alloc((size_t)768 * 768 * 2);
  size_t o_wp = alloc((size_t)768 * 768 * 2);
  u16* lnbuf = (u16*)(ws + o_ln);
  u16* pj    = (u16*)(ws + o_pj);
  u16* wqb   = (u16*)(ws + o_wq);
  u16* wpb   = (u16*)(ws + o_wp);
  const size_t NS = (size_t)8192 * 768;  // 6291456 elems
  // lnbuf region (3*NS u16) dead after qkv GEMM:
  u16* vnT = lnbuf;            // [768][8192] bf16
  u16* p0  = lnbuf + NS;       // PV partial 0; attn_out after reduce
  u16* p1  = lnbuf + 2 * NS;   // PV partial 1
  // vn rows (pj + 2*NS) dead after transpose64; QK doesn't read them -> rowsum lives there
  float* rowsum = (float*)(pj + 2 * NS);  // 8192 fp32
  // PV partials 2,3 live in d_out (25.2 MB = exactly 2*NS u16), overwritten by proj later
  u16* p2 = (u16*)d_out;
  u16* p3 = p2 + NS;
  size_t fixedEnd = off;
  u16* Sbuf = (u16*)(ws + fixedEnd);  // P' = exp(S*scale) bf16, 8192x8192 (134 MB)

  const float scale = 0.03608439182435161f;  // 1/sqrt(768)

  ln_cast_kernel<<<dim3(24576), dim3(256), 0, stream>>>(q, k, v, lw, lb, lnbuf);
  cast_f32_bf16<<<dim3(576), dim3(256), 0, stream>>>(Wq, wqb, 147456);
  cast_f32_bf16<<<dim3(576), dim3(256), 0, stream>>>(Wp, wpb, 147456);

  // qn/kn/vn = LN(x) @ W_qkv^T : [24576,768] x [768,768]^T
  gemm_bt<0><<<dim3(1152), dim3(256), 0, stream>>>(lnbuf, wqb, (void*)pj, (void*)pj,
      24576, 768, 768, 768, 768, 768, 1.0f, (const float*)nullptr, (float*)nullptr, 0);

  transpose64<<<dim3(1536), dim3(256), 0, stream>>>(pj + (size_t)16384 * 768, vnT);
  zero_f32<<<dim3(32), dim3(256), 0, stream>>>(rowsum, 8192);

  // P' = exp(qn @ kn^T * scale) (bf16), rowsum accumulated via atomics
  gemm_bt<1><<<dim3(4096), dim3(256), 0, stream>>>(
      pj, pj + NS, (void*)Sbuf, (void*)Sbuf,
      8192, 8192, 768, 768, 768, 8192, scale, (const float*)nullptr, rowsum, 0);

  // attn_partials = P' @ vn, 4-way split-K (z: K in [z*2048,(z+1)*2048))
  gemm_bt<0><<<dim3(384, 4), dim3(256), 0, stream>>>(
      Sbuf, vnT, (void*)p0, (void*)p2,
      8192, 768, 2048, 8192, 8192, 768, 1.0f, (const float*)nullptr, (float*)nullptr, NS);

  // attn_out = (p0+p1+p2+p3) / rowsum  -> p0 (bf16)
  reduce4_scale<<<dim3(3072), dim3(256), 0, stream>>>(p0, p1, p2, p3, rowsum, p0, (int)(NS / 8));

  // out = attn_out @ W_proj^T + b_proj  (fp32)
  gemm_bt<2><<<dim3(384), dim3(256), 0, stream>>>(p0, wpb, d_out, d_out,
      8192, 768, 768, 768, 768, 768, 1.0f, bp, (float*)nullptr, 0);
}